// Round 16
// baseline (154.341 us; speedup 1.0000x reference)
//
#include <hip/hip_runtime.h>

#define HH 20
#define WW 20

typedef _Float16 f16x8 __attribute__((ext_vector_type(8)));
typedef float    f32x4  __attribute__((ext_vector_type(4)));
typedef float    f32x4u __attribute__((ext_vector_type(4), aligned(4)));

// ---- DPP cross-lane (VALU pipe, not DS pipe) ----
template<int CTRL>
static __device__ __forceinline__ float dppf(float x) {
    return __int_as_float(__builtin_amdgcn_update_dpp(
        0, __float_as_int(x), CTRL, 0xF, 0xF, true));
}
static __device__ __forceinline__ float sum8_dpp(float x) {
    x += dppf<0xB1>(x);
    x += dppf<0x4E>(x);
    x += dppf<0x141>(x);
    return x;
}
static __device__ __forceinline__ float max8_dpp(float x) {
    x = fmaxf(x, dppf<0xB1>(x));
    x = fmaxf(x, dppf<0x4E>(x));
    x = fmaxf(x, dppf<0x141>(x));
    return x;
}
// Transpose-reduce over aligned 8-lane group, masks {1,2,7} (dual basis; bit-identical
// to the xor1/2/4 tree).
static __device__ __forceinline__ float bfly8_dpp(const float v[8], int lane) {
    const bool c1 = ((lane ^ (lane >> 2)) & 1);
    const bool c2 = (((lane >> 1) ^ (lane >> 2)) & 1);
    const bool c3 = ((lane >> 2) & 1);
    float k0 = c1 ? v[1] : v[0], s0 = c1 ? v[0] : v[1];
    float k1 = c1 ? v[3] : v[2], s1 = c1 ? v[2] : v[3];
    float k2 = c1 ? v[4] : v[5], s2 = c1 ? v[5] : v[4];
    float k3 = c1 ? v[6] : v[7], s3 = c1 ? v[7] : v[6];
    float w0 = k0 + dppf<0xB1>(s0);
    float w1 = k1 + dppf<0xB1>(s1);
    float w2 = k2 + dppf<0xB1>(s2);
    float w3 = k3 + dppf<0xB1>(s3);
    float ka = c2 ? w1 : w0, sa = c2 ? w0 : w1;
    float kb = c2 ? w2 : w3, sb = c2 ? w3 : w2;
    float za = ka + dppf<0x4E>(sa);
    float zb = kb + dppf<0x4E>(sb);
    float kr = c3 ? zb : za, sr = c3 ? za : zb;
    return kr + dppf<0x141>(sr);
}

// ---- prepack W -> fp16, k' = r*8 + ni reorder, K padded 72->96 ----
__global__ void prepack_w_kernel(const float* __restrict__ Wt, _Float16* __restrict__ bp) {
    int idx = blockIdx.x * 256 + threadIdx.x;     // 24576 total
    int oc = idx / 96, k = idx % 96;
    int r = k >> 3, ni = k & 7;
    float v = (r < 9) ? Wt[oc * 72 + ni * 9 + r] : 0.f;
    bp[idx] = (_Float16)v;
}

// Staging (768 segments, u16 stores). DS = dshift (block-uniform).
template<int DS>
__device__ __forceinline__ void stage_seg(const float* __restrict__ x,
                                          _Float16* A,
                                          int b, int h, int w0, int t) {
#pragma unroll
    for (int s = t; s < 768; s += 256) {               // (ci, ni, hr)
        int ci = s / 24;
        int r  = s % 24;
        int ni = r / 3, hr = r % 3;
        int hh = h - 1 + hr;
        bool hok = (hh >= 0) && (hh < HH);
        const int wlo = (DS == 0) ? (w0 - 1) : (DS < 0 ? 0 : WW - 4);
        const float* rowp = x + ((((b * 32 + ci) * 8 + ni) * HH + (hok ? hh : 0)) * WW) + wlo;
        f32x4u f4 = *(const f32x4u*)rowp;
        float vals[4];
        if (DS == 0)      { vals[0] = f4.x; vals[1] = f4.y; vals[2] = f4.z; vals[3] = f4.w; }
        else if (DS < 0)  { vals[0] = 0.f;  vals[1] = f4.x; vals[2] = f4.y; vals[3] = f4.z; }
        else              { vals[0] = f4.y; vals[1] = f4.z; vals[2] = f4.w; vals[3] = 0.f; }
        int kb = hr * 24 + ni;
#pragma unroll
        for (int j = 0; j < 4; ++j) {                  // window col c = w0-1+j
            float v = hok ? vals[j] : 0.f;
            _Float16 hv = (_Float16)v;
            if (j < 3)  A[ci * 96 + kb + j * 8] = hv;              // px0
            if (j > 0)  A[(32 + ci) * 96 + kb + (j - 1) * 8] = hv; // px1
        }
    }
}

// ---- fused conv + routing, 2 pixels/block, fp16 conv, DPP routing ----
// LDS region 20736 B (round-15 map). SINGLE CHANGE vs round 15:
// __launch_bounds__(256,6) — VGPR cap 85 >= 64 used; 6 blocks/CU static (was 4).
// Round-5 contrast: there cap(64) < live(~88) -> spill; here cap(85) > live(64).
__global__ __launch_bounds__(256, 6)
void caps_mfma15_kernel(const float* __restrict__ x,
                        const _Float16* __restrict__ bp,
                        const float* __restrict__ bias,
                        float* __restrict__ out) {
    __shared__ __align__(16) unsigned char region[20736];
    _Float16* A    = (_Float16*)region;                 // [64][96]
    float* bufbase = (float*)region;

    const int t  = threadIdx.x;
    const int wv = t >> 6;
    const int lr = t & 15;
    const int lg = (t >> 4) & 3;

    const int bi  = blockIdx.x;            // 3200 blocks
    const int b   = bi / 200;
    const int rem = bi % 200;
    const int h   = rem / 10;
    const int w0  = (rem % 10) * 2;

    // ---- zero k' pad [72,96) ----
#pragma unroll
    for (int e = t; e < 768; e += 256) {
        int row = e / 12, j = e % 12;
        ((unsigned int*)(A + row * 96 + 72))[j] = 0u;
    }

    // ---- stage x window ----
    const int dshift = (w0 == 0) ? -1 : (w0 == WW - 2) ? 1 : 0;
    if (dshift == 0)      stage_seg<0>(x, A, b, h, w0, t);
    else if (dshift < 0)  stage_seg<-1>(x, A, b, h, w0, t);
    else                  stage_seg<1>(x, A, b, h, w0, t);
    __syncthreads();                                    // (1) stage -> conv

    // ---- conv via fp16 MFMA: M=64, N=256, K=96 ----
    f32x4 acc[4][4];
#pragma unroll
    for (int i = 0; i < 4; ++i)
#pragma unroll
        for (int mt = 0; mt < 4; ++mt) acc[i][mt] = (f32x4){0.f, 0.f, 0.f, 0.f};

#pragma unroll
    for (int kst = 0; kst < 3; ++kst) {
        const int kb = kst * 32 + lg * 8;
        f16x8 af0 = *(const f16x8*)&A[(lr)      * 96 + kb];
        f16x8 af1 = *(const f16x8*)&A[(16 + lr) * 96 + kb];
        f16x8 af2 = *(const f16x8*)&A[(32 + lr) * 96 + kb];
        f16x8 af3 = *(const f16x8*)&A[(48 + lr) * 96 + kb];
#pragma unroll
        for (int i = 0; i < 4; ++i) {
            const int oc = (wv * 4 + i) * 16 + lr;
            f16x8 bv = *(const f16x8*)&bp[oc * 96 + kb];
            acc[i][0] = __builtin_amdgcn_mfma_f32_16x16x32_f16(af0, bv, acc[i][0], 0, 0, 0);
            acc[i][1] = __builtin_amdgcn_mfma_f32_16x16x32_f16(af1, bv, acc[i][1], 0, 0, 0);
            acc[i][2] = __builtin_amdgcn_mfma_f32_16x16x32_f16(af2, bv, acc[i][2], 0, 0, 0);
            acc[i][3] = __builtin_amdgcn_mfma_f32_16x16x32_f16(af3, bv, acc[i][3], 0, 0, 0);
        }
    }
    __syncthreads();                                    // (2) conv reads done -> overlay bufs

    // ---- wave-local transpose -> vr ----
    float* buf = bufbase + wv * 1152;                   // f32[32][36]
    f32x4 vr[2][4][2];                                  // [px][q]: votes[(t&7)*4+q][(t&~7)+0..7]
    const int ch_t = (t >> 5) & 1;
    const int c8   = t & 24;

#pragma unroll
    for (int p = 0; p < 2; ++p) {
#pragma unroll
        for (int ch = 0; ch < 2; ++ch) {
#pragma unroll
            for (int ii = 0; ii < 2; ++ii) {
#pragma unroll
                for (int mm = 0; mm < 2; ++mm) {
#pragma unroll
                    for (int r = 0; r < 4; ++r)
                        buf[(mm * 16 + lg * 4 + r) * 36 + ii * 16 + lr] =
                            acc[ch * 2 + ii][p * 2 + mm][r];
                }
            }
            if (ch_t == ch) {
#pragma unroll
                for (int q = 0; q < 4; ++q) {
                    int ciq = (t & 7) * 4 + q;
                    vr[p][q][0] = *(const f32x4*)&buf[ciq * 36 + c8];
                    vr[p][q][1] = *(const f32x4*)&buf[ciq * 36 + c8 + 4];
                }
            }
        }
    }

    // ---- routing: thread owns oc=t (co=t>>3, no=t&7) ----
    const int co = t >> 3;
    const int no = t & 7;
    const float bsv = bias[t];
    float* route0 = bufbase;                            // route_T[co][ci], [32][36]
    float* route1 = bufbase + 1152;
    float (*lg0)[37] = (float (*)[37])(bufbase + 2304); // logits[ci][co]
    float (*lg1)[37] = (float (*)[37])(bufbase + 2304 + 1184);
    float* actl = bufbase + 4672;                       // [wave][px][64], disjoint
    float dlog[2][4];
    float act[2];
    const int abase = wv * 128 + (t & 56);              // 8-group base (px stride 64)

    // iter 1 (uniform route): preact via q-sum + DPP butterfly; act via wave-private LDS
#pragma unroll
    for (int px = 0; px < 2; ++px) {
        float pj[8];
#pragma unroll
        for (int j = 0; j < 4; ++j) {
            pj[j]     = vr[px][0][0][j] + vr[px][1][0][j] + vr[px][2][0][j] + vr[px][3][0][j];
            pj[4 + j] = vr[px][0][1][j] + vr[px][1][1][j] + vr[px][2][1][j] + vr[px][3][1][j];
        }
        float p = fmaf(bfly8_dpp(pj, t), 0.03125f, bsv);
        float n2 = sum8_dpp(p * p);
        act[px] = p * n2 * __builtin_amdgcn_rcpf(1.f + n2) * __builtin_amdgcn_rsqf(n2 + 1e-9f);

        actl[wv * 128 + px * 64 + (t & 63)] = act[px];  // same-wave write -> broadcast reads
        f32x4 a0 = *(const f32x4*)&actl[abase + px * 64];
        f32x4 a1 = *(const f32x4*)&actl[abase + px * 64 + 4];
#pragma unroll
        for (int q = 0; q < 4; ++q) {
            f32x4 v0 = vr[px][q][0], v1 = vr[px][q][1];
            dlog[px][q] = v0.x * a0.x + v0.y * a0.y + v0.z * a0.z + v0.w * a0.w
                        + v1.x * a1.x + v1.y * a1.y + v1.z * a1.z + v1.w * a1.w;
        }
    }
    __syncthreads();                                    // (3) bufs read -> routing overlay
#pragma unroll
    for (int px = 0; px < 2; ++px) {
        float (*lgp)[37] = px ? lg1 : lg0;
#pragma unroll
        for (int q = 0; q < 4; ++q) lgp[no * 4 + q][co] = dlog[px][q];
    }
    __syncthreads();                                    // (4) logits -> softmax

    // iters 2..3
#pragma unroll
    for (int it = 1; it < 3; ++it) {
#pragma unroll
        for (int px = 0; px < 2; ++px) {                // softmax over co per ci-row (row = t>>3)
            float (*lgp)[37] = px ? lg1 : lg0;
            float* rtp = px ? route1 : route0;
            float l0 = lgp[co][no],      l1 = lgp[co][no + 8];
            float l2 = lgp[co][no + 16], l3 = lgp[co][no + 24];
            float m = max8_dpp(fmaxf(fmaxf(l0, l1), fmaxf(l2, l3)));
            float e0 = __expf(l0 - m), e1 = __expf(l1 - m);
            float e2 = __expf(l2 - m), e3 = __expf(l3 - m);
            float s = sum8_dpp(e0 + e1 + e2 + e3);
            float inv = __builtin_amdgcn_rcpf(s);
            rtp[(no)      * 36 + co] = e0 * inv;
            rtp[(no + 8)  * 36 + co] = e1 * inv;
            rtp[(no + 16) * 36 + co] = e2 * inv;
            rtp[(no + 24) * 36 + co] = e3 * inv;
        }
        __syncthreads();                                // (5/7) route -> preact

#pragma unroll
        for (int px = 0; px < 2; ++px) {
            float* rtp = px ? route1 : route0;
            f32x4 rv = *(const f32x4*)&rtp[co * 36 + (t & 7) * 4];
            float pj[8];
#pragma unroll
            for (int j = 0; j < 4; ++j) {
                pj[j]     = rv.x * vr[px][0][0][j] + rv.y * vr[px][1][0][j]
                          + rv.z * vr[px][2][0][j] + rv.w * vr[px][3][0][j];
                pj[4 + j] = rv.x * vr[px][0][1][j] + rv.y * vr[px][1][1][j]
                          + rv.z * vr[px][2][1][j] + rv.w * vr[px][3][1][j];
            }
            float p = bsv + bfly8_dpp(pj, t);
            float n2 = sum8_dpp(p * p);
            act[px] = p * n2 * __builtin_amdgcn_rcpf(1.f + n2) * __builtin_amdgcn_rsqf(n2 + 1e-9f);

            if (it == 1) {                              // distances via wave-private act_lds
                actl[wv * 128 + px * 64 + (t & 63)] = act[px];
                f32x4 a0 = *(const f32x4*)&actl[abase + px * 64];
                f32x4 a1 = *(const f32x4*)&actl[abase + px * 64 + 4];
                float (*lgp)[37] = px ? lg1 : lg0;
#pragma unroll
                for (int q = 0; q < 4; ++q) {
                    f32x4 v0 = vr[px][q][0], v1 = vr[px][q][1];
                    float d = v0.x * a0.x + v0.y * a0.y + v0.z * a0.z + v0.w * a0.w
                            + v1.x * a1.x + v1.y * a1.y + v1.z * a1.z + v1.w * a1.w;
                    dlog[px][q] += d;
                    lgp[no * 4 + q][co] = dlog[px][q];
                }
            }
        }
        if (it == 1) __syncthreads();                   // (6) logits -> softmax
    }

    // ---- out[b][oc=t][h][w0..w0+1] ----
    float2 o2 = make_float2(act[0], act[1]);
    *(float2*)&out[(b * 256 + t) * 400 + h * 20 + w0] = o2;
}

extern "C" void kernel_launch(void* const* d_in, const int* in_sizes, int n_in,
                              void* d_out, int out_size, void* d_ws, size_t ws_size,
                              hipStream_t stream) {
    const float* x    = (const float*)d_in[0];
    const float* Wt   = (const float*)d_in[1];
    const float* bias = (const float*)d_in[2];
    float* out        = (float*)d_out;
    _Float16* bp      = (_Float16*)d_ws;

    prepack_w_kernel<<<dim3(96), dim3(256), 0, stream>>>(Wt, bp);
    caps_mfma15_kernel<<<dim3(3200), dim3(256), 0, stream>>>(x, bp, bias, out);
}

// Round 17
// 58.145 us; speedup vs baseline: 2.6544x; 2.6544x over previous
//
#include <hip/hip_runtime.h>

#define HH 20
#define WW 20

typedef _Float16 f16x8 __attribute__((ext_vector_type(8)));
typedef float    f32x4  __attribute__((ext_vector_type(4)));
typedef float    f32x4u __attribute__((ext_vector_type(4), aligned(4)));

// ---- DPP cross-lane (VALU pipe, not DS pipe) ----
template<int CTRL>
static __device__ __forceinline__ float dppf(float x) {
    return __int_as_float(__builtin_amdgcn_update_dpp(
        0, __float_as_int(x), CTRL, 0xF, 0xF, true));
}
static __device__ __forceinline__ float sum8_dpp(float x) {
    x += dppf<0xB1>(x);
    x += dppf<0x4E>(x);
    x += dppf<0x141>(x);
    return x;
}
static __device__ __forceinline__ float max8_dpp(float x) {
    x = fmaxf(x, dppf<0xB1>(x));
    x = fmaxf(x, dppf<0x4E>(x));
    x = fmaxf(x, dppf<0x141>(x));
    return x;
}
// Transpose-reduce over aligned 8-lane group, masks {1,2,7} (dual basis; bit-identical
// to the xor1/2/4 tree).
static __device__ __forceinline__ float bfly8_dpp(const float v[8], int lane) {
    const bool c1 = ((lane ^ (lane >> 2)) & 1);
    const bool c2 = (((lane >> 1) ^ (lane >> 2)) & 1);
    const bool c3 = ((lane >> 2) & 1);
    float k0 = c1 ? v[1] : v[0], s0 = c1 ? v[0] : v[1];
    float k1 = c1 ? v[3] : v[2], s1 = c1 ? v[2] : v[3];
    float k2 = c1 ? v[4] : v[5], s2 = c1 ? v[5] : v[4];
    float k3 = c1 ? v[6] : v[7], s3 = c1 ? v[7] : v[6];
    float w0 = k0 + dppf<0xB1>(s0);
    float w1 = k1 + dppf<0xB1>(s1);
    float w2 = k2 + dppf<0xB1>(s2);
    float w3 = k3 + dppf<0xB1>(s3);
    float ka = c2 ? w1 : w0, sa = c2 ? w0 : w1;
    float kb = c2 ? w2 : w3, sb = c2 ? w3 : w2;
    float za = ka + dppf<0x4E>(sa);
    float zb = kb + dppf<0x4E>(sb);
    float kr = c3 ? zb : za, sr = c3 ? za : zb;
    return kr + dppf<0x141>(sr);
}

// ---- prepack W -> fp16, k' = r*8 + ni reorder, K padded 72->96 ----
__global__ void prepack_w_kernel(const float* __restrict__ Wt, _Float16* __restrict__ bp) {
    int idx = blockIdx.x * 256 + threadIdx.x;     // 24576 total
    int oc = idx / 96, k = idx % 96;
    int r = k >> 3, ni = k & 7;
    float v = (r < 9) ? Wt[oc * 72 + ni * 9 + r] : 0.f;
    bp[idx] = (_Float16)v;
}

// Staging (768 segments, u16 stores). DS = dshift (block-uniform).
template<int DS>
__device__ __forceinline__ void stage_seg(const float* __restrict__ x,
                                          _Float16* A,
                                          int b, int h, int w0, int t) {
#pragma unroll
    for (int s = t; s < 768; s += 256) {               // (ci, ni, hr)
        int ci = s / 24;
        int r  = s % 24;
        int ni = r / 3, hr = r % 3;
        int hh = h - 1 + hr;
        bool hok = (hh >= 0) && (hh < HH);
        const int wlo = (DS == 0) ? (w0 - 1) : (DS < 0 ? 0 : WW - 4);
        const float* rowp = x + ((((b * 32 + ci) * 8 + ni) * HH + (hok ? hh : 0)) * WW) + wlo;
        f32x4u f4 = *(const f32x4u*)rowp;
        float vals[4];
        if (DS == 0)      { vals[0] = f4.x; vals[1] = f4.y; vals[2] = f4.z; vals[3] = f4.w; }
        else if (DS < 0)  { vals[0] = 0.f;  vals[1] = f4.x; vals[2] = f4.y; vals[3] = f4.z; }
        else              { vals[0] = f4.y; vals[1] = f4.z; vals[2] = f4.w; vals[3] = 0.f; }
        int kb = hr * 24 + ni;
#pragma unroll
        for (int j = 0; j < 4; ++j) {                  // window col c = w0-1+j
            float v = hok ? vals[j] : 0.f;
            _Float16 hv = (_Float16)v;
            if (j < 3)  A[ci * 96 + kb + j * 8] = hv;              // px0
            if (j > 0)  A[(32 + ci) * 96 + kb + (j - 1) * 8] = hv; // px1
        }
    }
}

// ---- fused conv + routing, 2 pixels/block, per-pixel conv split ----
// LDS 30720 B:
//   A[64][96] fp16 @0 (12288 B)                  [stage .. px1 conv; routing overlays after B2]
//   wave bufs f32[32][36] @f32 3072 + wv*1152 (18432 B)  [transpose; DISJOINT from A so
//                                                 px0 transpose can't clobber px1's A reads]
//   routing overlay (after B2, spans A+bufs): route0@0, route1@1152,
//                                             lg0@2304, lg1@3488, actl@4672 (f32 idx)
// Register theory (round-16 lesson: VGPR+AGPR unified pool, 2048/CU in wave-units):
//   monolithic conv held acc(64)+vr(64)=128/thread -> pinned at 4 blocks/CU.
//   Per-pixel split: peak ~= vr0(32) + acc(32)||vr1(32) + temps ~= 90-100 <= 102 = cap@5.
__global__ __launch_bounds__(256, 5)
void caps_mfma16_kernel(const float* __restrict__ x,
                        const _Float16* __restrict__ bp,
                        const float* __restrict__ bias,
                        float* __restrict__ out) {
    __shared__ __align__(16) unsigned char region[30720];
    _Float16* A = (_Float16*)region;                    // [64][96]
    float* Rf   = (float*)region;

    const int t  = threadIdx.x;
    const int wv = t >> 6;
    const int lr = t & 15;
    const int lg = (t >> 4) & 3;

    const int bi  = blockIdx.x;            // 3200 blocks
    const int b   = bi / 200;
    const int rem = bi % 200;
    const int h   = rem / 10;
    const int w0  = (rem % 10) * 2;

    // ---- zero k' pad [72,96) ----
#pragma unroll
    for (int e = t; e < 768; e += 256) {
        int row = e / 12, j = e % 12;
        ((unsigned int*)(A + row * 96 + 72))[j] = 0u;
    }

    // ---- stage x window ----
    const int dshift = (w0 == 0) ? -1 : (w0 == WW - 2) ? 1 : 0;
    if (dshift == 0)      stage_seg<0>(x, A, b, h, w0, t);
    else if (dshift < 0)  stage_seg<-1>(x, A, b, h, w0, t);
    else                  stage_seg<1>(x, A, b, h, w0, t);
    __syncthreads();                                    // (B1) stage -> conv

    // ---- per-pixel conv + wave-local transpose ----
    float* buf = Rf + 3072 + wv * 1152;                 // f32[32][36], disjoint from A
    f32x4 vr[2][4][2];                                  // [px][q]: votes[(t&7)*4+q][(t&~7)+0..7]
    const int ch_t = (t >> 5) & 1;
    const int c8   = t & 24;

#pragma unroll
    for (int mh = 0; mh < 2; ++mh) {                    // pixel
        f32x4 acc[4][2];                                // [N-tile i][row-half]
#pragma unroll
        for (int i = 0; i < 4; ++i)
#pragma unroll
            for (int mm = 0; mm < 2; ++mm) acc[i][mm] = (f32x4){0.f, 0.f, 0.f, 0.f};

#pragma unroll
        for (int kst = 0; kst < 3; ++kst) {
            const int kb = kst * 32 + lg * 8;
            f16x8 af0 = *(const f16x8*)&A[(mh * 32 + lr)      * 96 + kb];
            f16x8 af1 = *(const f16x8*)&A[(mh * 32 + 16 + lr) * 96 + kb];
#pragma unroll
            for (int i = 0; i < 4; ++i) {
                const int oc = (wv * 4 + i) * 16 + lr;
                f16x8 bv = *(const f16x8*)&bp[oc * 96 + kb];
                acc[i][0] = __builtin_amdgcn_mfma_f32_16x16x32_f16(af0, bv, acc[i][0], 0, 0, 0);
                acc[i][1] = __builtin_amdgcn_mfma_f32_16x16x32_f16(af1, bv, acc[i][1], 0, 0, 0);
            }
        }
        // transpose this pixel (wave-private buf, disjoint from A -> no barrier)
#pragma unroll
        for (int ch = 0; ch < 2; ++ch) {
#pragma unroll
            for (int ii = 0; ii < 2; ++ii)
#pragma unroll
                for (int mm = 0; mm < 2; ++mm)
#pragma unroll
                    for (int r = 0; r < 4; ++r)
                        buf[(mm * 16 + lg * 4 + r) * 36 + ii * 16 + lr] =
                            acc[ch * 2 + ii][mm][r];
            if (ch_t == ch) {
#pragma unroll
                for (int q = 0; q < 4; ++q) {
                    int ciq = (t & 7) * 4 + q;
                    vr[mh][q][0] = *(const f32x4*)&buf[ciq * 36 + c8];
                    vr[mh][q][1] = *(const f32x4*)&buf[ciq * 36 + c8 + 4];
                }
            }
        }
    }
    __syncthreads();                                    // (B2) A+buf reads done -> routing overlay

    // ---- routing: thread owns oc=t (co=t>>3, no=t&7) ----
    const int co = t >> 3;
    const int no = t & 7;
    const float bsv = bias[t];
    float* route0 = Rf;                                 // route_T[co][ci], [32][36]
    float* route1 = Rf + 1152;
    float (*lg0)[37] = (float (*)[37])(Rf + 2304);      // logits[ci][co]
    float (*lg1)[37] = (float (*)[37])(Rf + 2304 + 1184);
    float* actl = Rf + 4672;                            // [wave][px][64]
    float dlog[2][4];
    float act[2];
    const int abase = wv * 128 + (t & 56);              // 8-group base (px stride 64)

    // iter 1 (uniform route): preact via q-sum + DPP butterfly; act via wave-private LDS
#pragma unroll
    for (int px = 0; px < 2; ++px) {
        float pj[8];
#pragma unroll
        for (int j = 0; j < 4; ++j) {
            pj[j]     = vr[px][0][0][j] + vr[px][1][0][j] + vr[px][2][0][j] + vr[px][3][0][j];
            pj[4 + j] = vr[px][0][1][j] + vr[px][1][1][j] + vr[px][2][1][j] + vr[px][3][1][j];
        }
        float p = fmaf(bfly8_dpp(pj, t), 0.03125f, bsv);
        float n2 = sum8_dpp(p * p);
        act[px] = p * n2 * __builtin_amdgcn_rcpf(1.f + n2) * __builtin_amdgcn_rsqf(n2 + 1e-9f);

        actl[wv * 128 + px * 64 + (t & 63)] = act[px];  // same-wave write -> broadcast reads
        f32x4 a0 = *(const f32x4*)&actl[abase + px * 64];
        f32x4 a1 = *(const f32x4*)&actl[abase + px * 64 + 4];
#pragma unroll
        for (int q = 0; q < 4; ++q) {
            f32x4 v0 = vr[px][q][0], v1 = vr[px][q][1];
            dlog[px][q] = v0.x * a0.x + v0.y * a0.y + v0.z * a0.z + v0.w * a0.w
                        + v1.x * a1.x + v1.y * a1.y + v1.z * a1.z + v1.w * a1.w;
        }
    }
    __syncthreads();                                    // (B3) overlay safe block-wide
#pragma unroll
    for (int px = 0; px < 2; ++px) {
        float (*lgp)[37] = px ? lg1 : lg0;
#pragma unroll
        for (int q = 0; q < 4; ++q) lgp[no * 4 + q][co] = dlog[px][q];
    }
    __syncthreads();                                    // (B4) logits -> softmax

    // iters 2..3
#pragma unroll
    for (int it = 1; it < 3; ++it) {
#pragma unroll
        for (int px = 0; px < 2; ++px) {                // softmax over co per ci-row (row = t>>3)
            float (*lgp)[37] = px ? lg1 : lg0;
            float* rtp = px ? route1 : route0;
            float l0 = lgp[co][no],      l1 = lgp[co][no + 8];
            float l2 = lgp[co][no + 16], l3 = lgp[co][no + 24];
            float m = max8_dpp(fmaxf(fmaxf(l0, l1), fmaxf(l2, l3)));
            float e0 = __expf(l0 - m), e1 = __expf(l1 - m);
            float e2 = __expf(l2 - m), e3 = __expf(l3 - m);
            float s = sum8_dpp(e0 + e1 + e2 + e3);
            float inv = __builtin_amdgcn_rcpf(s);
            rtp[(no)      * 36 + co] = e0 * inv;
            rtp[(no + 8)  * 36 + co] = e1 * inv;
            rtp[(no + 16) * 36 + co] = e2 * inv;
            rtp[(no + 24) * 36 + co] = e3 * inv;
        }
        __syncthreads();                                // (B5/B7) route -> preact

#pragma unroll
        for (int px = 0; px < 2; ++px) {
            float* rtp = px ? route1 : route0;
            f32x4 rv = *(const f32x4*)&rtp[co * 36 + (t & 7) * 4];
            float pj[8];
#pragma unroll
            for (int j = 0; j < 4; ++j) {
                pj[j]     = rv.x * vr[px][0][0][j] + rv.y * vr[px][1][0][j]
                          + rv.z * vr[px][2][0][j] + rv.w * vr[px][3][0][j];
                pj[4 + j] = rv.x * vr[px][0][1][j] + rv.y * vr[px][1][1][j]
                          + rv.z * vr[px][2][1][j] + rv.w * vr[px][3][1][j];
            }
            float p = bsv + bfly8_dpp(pj, t);
            float n2 = sum8_dpp(p * p);
            act[px] = p * n2 * __builtin_amdgcn_rcpf(1.f + n2) * __builtin_amdgcn_rsqf(n2 + 1e-9f);

            if (it == 1) {                              // distances via wave-private act_lds
                actl[wv * 128 + px * 64 + (t & 63)] = act[px];
                f32x4 a0 = *(const f32x4*)&actl[abase + px * 64];
                f32x4 a1 = *(const f32x4*)&actl[abase + px * 64 + 4];
                float (*lgp)[37] = px ? lg1 : lg0;
#pragma unroll
                for (int q = 0; q < 4; ++q) {
                    f32x4 v0 = vr[px][q][0], v1 = vr[px][q][1];
                    float d = v0.x * a0.x + v0.y * a0.y + v0.z * a0.z + v0.w * a0.w
                            + v1.x * a1.x + v1.y * a1.y + v1.z * a1.z + v1.w * a1.w;
                    dlog[px][q] += d;
                    lgp[no * 4 + q][co] = dlog[px][q];
                }
            }
        }
        if (it == 1) __syncthreads();                   // (B6) logits -> softmax
    }

    // ---- out[b][oc=t][h][w0..w0+1] ----
    float2 o2 = make_float2(act[0], act[1]);
    *(float2*)&out[(b * 256 + t) * 400 + h * 20 + w0] = o2;
}

extern "C" void kernel_launch(void* const* d_in, const int* in_sizes, int n_in,
                              void* d_out, int out_size, void* d_ws, size_t ws_size,
                              hipStream_t stream) {
    const float* x    = (const float*)d_in[0];
    const float* Wt   = (const float*)d_in[1];
    const float* bias = (const float*)d_in[2];
    float* out        = (float*)d_out;
    _Float16* bp      = (_Float16*)d_ws;

    prepack_w_kernel<<<dim3(96), dim3(256), 0, stream>>>(Wt, bp);
    caps_mfma16_kernel<<<dim3(3200), dim3(256), 0, stream>>>(x, bp, bias, out);
}

// Round 18
// 48.675 us; speedup vs baseline: 3.1709x; 1.1946x over previous
//
#include <hip/hip_runtime.h>

#define HH 20
#define WW 20

typedef _Float16 f16x8 __attribute__((ext_vector_type(8)));
typedef float    f32x4  __attribute__((ext_vector_type(4)));
typedef float    f32x4u __attribute__((ext_vector_type(4), aligned(4)));

// ---- DPP cross-lane (VALU pipe, not DS pipe) ----
template<int CTRL>
static __device__ __forceinline__ float dppf(float x) {
    return __int_as_float(__builtin_amdgcn_update_dpp(
        0, __float_as_int(x), CTRL, 0xF, 0xF, true));
}
static __device__ __forceinline__ float sum8_dpp(float x) {
    x += dppf<0xB1>(x);
    x += dppf<0x4E>(x);
    x += dppf<0x141>(x);
    return x;
}
static __device__ __forceinline__ float max8_dpp(float x) {
    x = fmaxf(x, dppf<0xB1>(x));
    x = fmaxf(x, dppf<0x4E>(x));
    x = fmaxf(x, dppf<0x141>(x));
    return x;
}
// Transpose-reduce over aligned 8-lane group, masks {1,2,7} (dual basis; bit-identical
// to the xor1/2/4 tree).
static __device__ __forceinline__ float bfly8_dpp(const float v[8], int lane) {
    const bool c1 = ((lane ^ (lane >> 2)) & 1);
    const bool c2 = (((lane >> 1) ^ (lane >> 2)) & 1);
    const bool c3 = ((lane >> 2) & 1);
    float k0 = c1 ? v[1] : v[0], s0 = c1 ? v[0] : v[1];
    float k1 = c1 ? v[3] : v[2], s1 = c1 ? v[2] : v[3];
    float k2 = c1 ? v[4] : v[5], s2 = c1 ? v[5] : v[4];
    float k3 = c1 ? v[6] : v[7], s3 = c1 ? v[7] : v[6];
    float w0 = k0 + dppf<0xB1>(s0);
    float w1 = k1 + dppf<0xB1>(s1);
    float w2 = k2 + dppf<0xB1>(s2);
    float w3 = k3 + dppf<0xB1>(s3);
    float ka = c2 ? w1 : w0, sa = c2 ? w0 : w1;
    float kb = c2 ? w2 : w3, sb = c2 ? w3 : w2;
    float za = ka + dppf<0x4E>(sa);
    float zb = kb + dppf<0x4E>(sb);
    float kr = c3 ? zb : za, sr = c3 ? za : zb;
    return kr + dppf<0x141>(sr);
}

// ---- prepack W -> fp16, k' = r*8 + ni reorder, K padded 72->96 ----
__global__ void prepack_w_kernel(const float* __restrict__ Wt, _Float16* __restrict__ bp) {
    int idx = blockIdx.x * 256 + threadIdx.x;     // 24576 total
    int oc = idx / 96, k = idx % 96;
    int r = k >> 3, ni = k & 7;
    float v = (r < 9) ? Wt[oc * 72 + ni * 9 + r] : 0.f;
    bp[idx] = (_Float16)v;
}

// Staging (768 segments, u16 stores). DS = dshift (block-uniform).
template<int DS>
__device__ __forceinline__ void stage_seg(const float* __restrict__ x,
                                          _Float16* A,
                                          int b, int h, int w0, int t) {
#pragma unroll
    for (int s = t; s < 768; s += 256) {               // (ci, ni, hr)
        int ci = s / 24;
        int r  = s % 24;
        int ni = r / 3, hr = r % 3;
        int hh = h - 1 + hr;
        bool hok = (hh >= 0) && (hh < HH);
        const int wlo = (DS == 0) ? (w0 - 1) : (DS < 0 ? 0 : WW - 4);
        const float* rowp = x + ((((b * 32 + ci) * 8 + ni) * HH + (hok ? hh : 0)) * WW) + wlo;
        f32x4u f4 = *(const f32x4u*)rowp;
        float vals[4];
        if (DS == 0)      { vals[0] = f4.x; vals[1] = f4.y; vals[2] = f4.z; vals[3] = f4.w; }
        else if (DS < 0)  { vals[0] = 0.f;  vals[1] = f4.x; vals[2] = f4.y; vals[3] = f4.z; }
        else              { vals[0] = f4.y; vals[1] = f4.z; vals[2] = f4.w; vals[3] = 0.f; }
        int kb = hr * 24 + ni;
#pragma unroll
        for (int j = 0; j < 4; ++j) {                  // window col c = w0-1+j
            float v = hok ? vals[j] : 0.f;
            _Float16 hv = (_Float16)v;
            if (j < 3)  A[ci * 96 + kb + j * 8] = hv;              // px0
            if (j > 0)  A[(32 + ci) * 96 + kb + (j - 1) * 8] = hv; // px1
        }
    }
}

// ---- fused conv + routing, 2 pixels/block, fp16 conv, DPP routing ----
// PROVEN BEST (round 15: 44.0 us steady, no spill). LDS region 20736 B:
//   phase A  : A[64][96] fp16 @0 (12288 B)
//   phase B  : wave bufs f32[32][36] @ wv*4608 (18432 B)
//   phase C  : route0/1 [co][ci] @0/+1152, lg0/1 [ci][37] @+2304/+3488 (f32 idx)
//   always   : act_lds f32 @+4672: [wave 4][px 2][64] (same-wave write->read, no barrier)
// Register reality (rounds 16/17 lesson): vr(64)+acc(64 AGPR-side)+temps needs the
// full 128/thread budget -> 4 blocks/CU is this algorithm's natural occupancy.
// (256,5)/(256,6)/per-pixel-split all spill (WRITE_SIZE 77-487 MB). Do not tighten.
__global__ __launch_bounds__(256, 4)
void caps_mfma17_kernel(const float* __restrict__ x,
                        const _Float16* __restrict__ bp,
                        const float* __restrict__ bias,
                        float* __restrict__ out) {
    __shared__ __align__(16) unsigned char region[20736];
    _Float16* A    = (_Float16*)region;                 // [64][96]
    float* bufbase = (float*)region;

    const int t  = threadIdx.x;
    const int wv = t >> 6;
    const int lr = t & 15;
    const int lg = (t >> 4) & 3;

    const int bi  = blockIdx.x;            // 3200 blocks
    const int b   = bi / 200;
    const int rem = bi % 200;
    const int h   = rem / 10;
    const int w0  = (rem % 10) * 2;

    // ---- zero k' pad [72,96) ----
#pragma unroll
    for (int e = t; e < 768; e += 256) {
        int row = e / 12, j = e % 12;
        ((unsigned int*)(A + row * 96 + 72))[j] = 0u;
    }

    // ---- stage x window ----
    const int dshift = (w0 == 0) ? -1 : (w0 == WW - 2) ? 1 : 0;
    if (dshift == 0)      stage_seg<0>(x, A, b, h, w0, t);
    else if (dshift < 0)  stage_seg<-1>(x, A, b, h, w0, t);
    else                  stage_seg<1>(x, A, b, h, w0, t);
    __syncthreads();                                    // (1) stage -> conv

    // ---- conv via fp16 MFMA: M=64, N=256, K=96 ----
    f32x4 acc[4][4];
#pragma unroll
    for (int i = 0; i < 4; ++i)
#pragma unroll
        for (int mt = 0; mt < 4; ++mt) acc[i][mt] = (f32x4){0.f, 0.f, 0.f, 0.f};

#pragma unroll
    for (int kst = 0; kst < 3; ++kst) {
        const int kb = kst * 32 + lg * 8;
        f16x8 af0 = *(const f16x8*)&A[(lr)      * 96 + kb];
        f16x8 af1 = *(const f16x8*)&A[(16 + lr) * 96 + kb];
        f16x8 af2 = *(const f16x8*)&A[(32 + lr) * 96 + kb];
        f16x8 af3 = *(const f16x8*)&A[(48 + lr) * 96 + kb];
#pragma unroll
        for (int i = 0; i < 4; ++i) {
            const int oc = (wv * 4 + i) * 16 + lr;
            f16x8 bv = *(const f16x8*)&bp[oc * 96 + kb];
            acc[i][0] = __builtin_amdgcn_mfma_f32_16x16x32_f16(af0, bv, acc[i][0], 0, 0, 0);
            acc[i][1] = __builtin_amdgcn_mfma_f32_16x16x32_f16(af1, bv, acc[i][1], 0, 0, 0);
            acc[i][2] = __builtin_amdgcn_mfma_f32_16x16x32_f16(af2, bv, acc[i][2], 0, 0, 0);
            acc[i][3] = __builtin_amdgcn_mfma_f32_16x16x32_f16(af3, bv, acc[i][3], 0, 0, 0);
        }
    }
    __syncthreads();                                    // (2) conv reads done -> overlay bufs

    // ---- wave-local transpose -> vr ----
    float* buf = bufbase + wv * 1152;                   // f32[32][36]
    f32x4 vr[2][4][2];                                  // [px][q]: votes[(t&7)*4+q][(t&~7)+0..7]
    const int ch_t = (t >> 5) & 1;
    const int c8   = t & 24;

#pragma unroll
    for (int p = 0; p < 2; ++p) {
#pragma unroll
        for (int ch = 0; ch < 2; ++ch) {
#pragma unroll
            for (int ii = 0; ii < 2; ++ii) {
#pragma unroll
                for (int mm = 0; mm < 2; ++mm) {
#pragma unroll
                    for (int r = 0; r < 4; ++r)
                        buf[(mm * 16 + lg * 4 + r) * 36 + ii * 16 + lr] =
                            acc[ch * 2 + ii][p * 2 + mm][r];
                }
            }
            if (ch_t == ch) {
#pragma unroll
                for (int q = 0; q < 4; ++q) {
                    int ciq = (t & 7) * 4 + q;
                    vr[p][q][0] = *(const f32x4*)&buf[ciq * 36 + c8];
                    vr[p][q][1] = *(const f32x4*)&buf[ciq * 36 + c8 + 4];
                }
            }
        }
    }

    // ---- routing: thread owns oc=t (co=t>>3, no=t&7) ----
    const int co = t >> 3;
    const int no = t & 7;
    const float bsv = bias[t];
    float* route0 = bufbase;                            // route_T[co][ci], [32][36]
    float* route1 = bufbase + 1152;
    float (*lg0)[37] = (float (*)[37])(bufbase + 2304); // logits[ci][co]
    float (*lg1)[37] = (float (*)[37])(bufbase + 2304 + 1184);
    float* actl = bufbase + 4672;                       // [wave][px][64], disjoint
    float dlog[2][4];
    float act[2];
    const int abase = wv * 128 + (t & 56);              // 8-group base (px stride 64)

    // iter 1 (uniform route): preact via q-sum + DPP butterfly; act via wave-private LDS
#pragma unroll
    for (int px = 0; px < 2; ++px) {
        float pj[8];
#pragma unroll
        for (int j = 0; j < 4; ++j) {
            pj[j]     = vr[px][0][0][j] + vr[px][1][0][j] + vr[px][2][0][j] + vr[px][3][0][j];
            pj[4 + j] = vr[px][0][1][j] + vr[px][1][1][j] + vr[px][2][1][j] + vr[px][3][1][j];
        }
        float p = fmaf(bfly8_dpp(pj, t), 0.03125f, bsv);
        float n2 = sum8_dpp(p * p);
        act[px] = p * n2 * __builtin_amdgcn_rcpf(1.f + n2) * __builtin_amdgcn_rsqf(n2 + 1e-9f);

        actl[wv * 128 + px * 64 + (t & 63)] = act[px];  // same-wave write -> broadcast reads
        f32x4 a0 = *(const f32x4*)&actl[abase + px * 64];
        f32x4 a1 = *(const f32x4*)&actl[abase + px * 64 + 4];
#pragma unroll
        for (int q = 0; q < 4; ++q) {
            f32x4 v0 = vr[px][q][0], v1 = vr[px][q][1];
            dlog[px][q] = v0.x * a0.x + v0.y * a0.y + v0.z * a0.z + v0.w * a0.w
                        + v1.x * a1.x + v1.y * a1.y + v1.z * a1.z + v1.w * a1.w;
        }
    }
    __syncthreads();                                    // (3) bufs read -> routing overlay
#pragma unroll
    for (int px = 0; px < 2; ++px) {
        float (*lgp)[37] = px ? lg1 : lg0;
#pragma unroll
        for (int q = 0; q < 4; ++q) lgp[no * 4 + q][co] = dlog[px][q];
    }
    __syncthreads();                                    // (4) logits -> softmax

    // iters 2..3
#pragma unroll
    for (int it = 1; it < 3; ++it) {
#pragma unroll
        for (int px = 0; px < 2; ++px) {                // softmax over co per ci-row (row = t>>3)
            float (*lgp)[37] = px ? lg1 : lg0;
            float* rtp = px ? route1 : route0;
            float l0 = lgp[co][no],      l1 = lgp[co][no + 8];
            float l2 = lgp[co][no + 16], l3 = lgp[co][no + 24];
            float m = max8_dpp(fmaxf(fmaxf(l0, l1), fmaxf(l2, l3)));
            float e0 = __expf(l0 - m), e1 = __expf(l1 - m);
            float e2 = __expf(l2 - m), e3 = __expf(l3 - m);
            float s = sum8_dpp(e0 + e1 + e2 + e3);
            float inv = __builtin_amdgcn_rcpf(s);
            rtp[(no)      * 36 + co] = e0 * inv;
            rtp[(no + 8)  * 36 + co] = e1 * inv;
            rtp[(no + 16) * 36 + co] = e2 * inv;
            rtp[(no + 24) * 36 + co] = e3 * inv;
        }
        __syncthreads();                                // (5/7) route -> preact

#pragma unroll
        for (int px = 0; px < 2; ++px) {
            float* rtp = px ? route1 : route0;
            f32x4 rv = *(const f32x4*)&rtp[co * 36 + (t & 7) * 4];
            float pj[8];
#pragma unroll
            for (int j = 0; j < 4; ++j) {
                pj[j]     = rv.x * vr[px][0][0][j] + rv.y * vr[px][1][0][j]
                          + rv.z * vr[px][2][0][j] + rv.w * vr[px][3][0][j];
                pj[4 + j] = rv.x * vr[px][0][1][j] + rv.y * vr[px][1][1][j]
                          + rv.z * vr[px][2][1][j] + rv.w * vr[px][3][1][j];
            }
            float p = bsv + bfly8_dpp(pj, t);
            float n2 = sum8_dpp(p * p);
            act[px] = p * n2 * __builtin_amdgcn_rcpf(1.f + n2) * __builtin_amdgcn_rsqf(n2 + 1e-9f);

            if (it == 1) {                              // distances via wave-private act_lds
                actl[wv * 128 + px * 64 + (t & 63)] = act[px];
                f32x4 a0 = *(const f32x4*)&actl[abase + px * 64];
                f32x4 a1 = *(const f32x4*)&actl[abase + px * 64 + 4];
                float (*lgp)[37] = px ? lg1 : lg0;
#pragma unroll
                for (int q = 0; q < 4; ++q) {
                    f32x4 v0 = vr[px][q][0], v1 = vr[px][q][1];
                    float d = v0.x * a0.x + v0.y * a0.y + v0.z * a0.z + v0.w * a0.w
                            + v1.x * a1.x + v1.y * a1.y + v1.z * a1.z + v1.w * a1.w;
                    dlog[px][q] += d;
                    lgp[no * 4 + q][co] = dlog[px][q];
                }
            }
        }
        if (it == 1) __syncthreads();                   // (6) logits -> softmax
    }

    // ---- out[b][oc=t][h][w0..w0+1] ----
    float2 o2 = make_float2(act[0], act[1]);
    *(float2*)&out[(b * 256 + t) * 400 + h * 20 + w0] = o2;
}

extern "C" void kernel_launch(void* const* d_in, const int* in_sizes, int n_in,
                              void* d_out, int out_size, void* d_ws, size_t ws_size,
                              hipStream_t stream) {
    const float* x    = (const float*)d_in[0];
    const float* Wt   = (const float*)d_in[1];
    const float* bias = (const float*)d_in[2];
    float* out        = (float*)d_out;
    _Float16* bp      = (_Float16*)d_ws;

    prepack_w_kernel<<<dim3(96), dim3(256), 0, stream>>>(Wt, bp);
    caps_mfma17_kernel<<<dim3(3200), dim3(256), 0, stream>>>(x, bp, bias, out);
}